// Round 6
// baseline (200.579 us; speedup 1.0000x reference)
//
#include <hip/hip_runtime.h>
#include <math.h>

// ---------------------------------------------------------------------------
// Round 10: VALU-op reduction on the verified R8 structure (1 tile/wave).
//  - 2-tile ILP abandoned: two attempts (R5, R9) both failed numerically;
//    fold chain is chaotic at the threshold level under heavy restructure.
//  - v_perm_b32 packing for all activation hi/lo splits: one instruction
//    per packed dword instead of per-short shift/and/or chains. Pure bit
//    movement, truncation semantics identical to split_trunc -> VALUES
//    BIT-IDENTICAL to R8. Est. -20% VALU ops per tile.
//  - Explicit register reuse: layer-0 output overwrites d1, layer-1 output
//    overwrites d2, one shared bv[] for bias vectors -> target combined
//    VGPR+AGPR <=128 for 4 waves/SIMD (R8 was ~160 -> 3 waves/SIMD).
//  - Everything else (helpers, build_frags, kperm32, grid) verbatim R8.
// ---------------------------------------------------------------------------

typedef short bf16x8 __attribute__((ext_vector_type(8)));
typedef float f32x4  __attribute__((ext_vector_type(4)));
typedef float f32x16 __attribute__((ext_vector_type(16)));

#define MFMA32(A, B, C) __builtin_amdgcn_mfma_f32_32x32x16_bf16((A), (B), (C), 0, 0, 0)
#define PBOUND 0.99999f /* 1 - 1e-5 */

static __device__ __forceinline__ float artanh_c(float n) {
    float z = fminf(n, PBOUND);
    return 0.5f * __logf((1.0f + z) / (1.0f - z));
}
static __device__ __forceinline__ float tanh_pos(float n) {
    float e = __expf(-2.0f * n);
    return (1.0f - e) / (1.0f + e);
}
// row r is held by lanes r and r+32: single-swap reduction, broadcast to both
static __device__ __forceinline__ float red2h(float v) {
    return v + __shfl_xor(v, 32);
}

// pack hi16(x0) into low half, hi16(x1) into high half — ONE v_perm_b32.
// perm(src0,src1,sel): sel bytes 0-3 pick from src1, 4-7 from src0.
static __device__ __forceinline__ unsigned pack_hi2(unsigned u0, unsigned u1) {
    return __builtin_amdgcn_perm(u1, u0, 0x07060302);
}
// truncation split of a float pair -> packed hi dword + packed lo dword.
// Semantics identical to R8's split_trunc (truncate hi; lo = bf16_trunc(x-hi)).
static __device__ __forceinline__ void split_pack2(float x0, float x1,
                                                   unsigned& hw, unsigned& lw) {
    unsigned u0 = __builtin_bit_cast(unsigned, x0);
    unsigned u1 = __builtin_bit_cast(unsigned, x1);
    hw = pack_hi2(u0, u1);
    float r0 = x0 - __builtin_bit_cast(float, u0 & 0xFFFF0000u);
    float r1 = x1 - __builtin_bit_cast(float, u1 & 0xFFFF0000u);
    lw = pack_hi2(__builtin_bit_cast(unsigned, r0), __builtin_bit_cast(unsigned, r1));
}

// K-slot s (0..63) of a 64-dim layer holds natural feature kperm32(s) of the
// previous layer's D output (verified R8).
static __device__ __forceinline__ int kperm32(int s) {
    return (s >> 5) * 32 + (((s >> 2) & 1) + 2 * ((s >> 4) & 1)) * 8 +
           ((s >> 3) & 1) * 4 + (s & 3);
}

static __device__ __forceinline__ f32x16 zero16() {
    f32x16 z;
#pragma unroll
    for (int r = 0; r < 16; ++r) z[r] = 0.0f;
    return z;
}

template <int NV>
static __device__ __forceinline__ float dotred32(const f32x16* a, const f32x16* b) {
    float p = 0.0f;
#pragma unroll
    for (int v = 0; v < NV; ++v)
#pragma unroll
        for (int r = 0; r < 16; ++r) p = fmaf(a[v][r], b[v][r], p);
    return red2h(p);
}

// expmap with pending scale: true vec = lam*d. Updates lam, X2 (true |.|^2).
template <int NV>
static __device__ __forceinline__ void expmap_fold32(const f32x16* d, float& lam, float& X2) {
    float p = 0.0f;
#pragma unroll
    for (int v = 0; v < NV; ++v)
#pragma unroll
        for (int r = 0; r < 16; ++r) p = fmaf(d[v][r], d[v][r], p);
    p = red2h(p);
    float nU = fmaxf(lam * sqrtf(p), 1e-15f);
    float th = tanh_pos(nU);
    lam = lam * th / nU;
    X2 = th * th;
}

static __device__ __forceinline__ void logmap_fold(float& lam, float X2) {
    float n = fmaxf(sqrtf(X2), 1e-15f);
    lam *= artanh_c(n) / n;
}

// d <- raw(mobius_add(lam*d, bias)); lam <- 1/den; X2 updated analytically
template <int NV>
static __device__ __forceinline__ void mobius_bias_fold32(f32x16* d, const f32x16* bv,
                                                          float& lam, float& X2, float b2) {
    float C = dotred32<NV>(d, bv);
    float xy = lam * C;
    float a = 1.0f + 2.0f * xy + b2;
    float b = 1.0f - X2;
    float den = fmaxf(fmaf(X2, b2, 1.0f + 2.0f * xy), 1e-15f);
    float inv = 1.0f / den;
    float A = a * lam;
#pragma unroll
    for (int v = 0; v < NV; ++v)
#pragma unroll
        for (int r = 0; r < 16; ++r) d[v][r] = fmaf(A, d[v][r], b * bv[v][r]);
    lam = inv;
    X2 = (a * a * X2 + 2.0f * a * b * xy + b * b * b2) * (inv * inv);
}

// split the 32 D-regs (2 x f32x16) into the 4 next-layer B-frag hi/lo pairs.
// Block kt <- regs 8*(kt&1)..+7 of d[kt>>1]; perm-packed (values = R8).
static __device__ __forceinline__ void split_d32(const f32x16 d[2], bf16x8 bh[4], bf16x8 bl[4]) {
#pragma unroll
    for (int kt = 0; kt < 4; ++kt) {
        const int v = kt >> 1, o = 8 * (kt & 1);
        uint4 hw, lw;
        split_pack2(d[v][o + 0], d[v][o + 1], hw.x, lw.x);
        split_pack2(d[v][o + 2], d[v][o + 3], hw.y, lw.y);
        split_pack2(d[v][o + 4], d[v][o + 5], hw.z, lw.z);
        split_pack2(d[v][o + 6], d[v][o + 7], hw.w, lw.w);
        bh[kt] = __builtin_bit_cast(bf16x8, hw);
        bl[kt] = __builtin_bit_cast(bf16x8, lw);
    }
}

// bias vector in D-register order: reg-group g holds features off+8g+4h+(0..3)
static __device__ __forceinline__ f32x16 loadb(const float* __restrict__ b, int off, int h) {
    f32x16 r;
#pragma unroll
    for (int g = 0; g < 4; ++g) {
        f32x4 v = *(const f32x4*)(b + off + g * 8 + h * 4);
#pragma unroll
        for (int k = 0; k < 4; ++k) r[g * 4 + k] = v[k];
    }
    return r;
}

// branch: lane (r,h) loads row cols [h*8..h*8+7] and [16+h*8..+7] (natural
// B k-order), logmap fold, perm-packed split, matvec, expmap fold.
static __device__ __forceinline__ void branch_stage32(const float* __restrict__ x, size_t row,
                                                      int h, int lane, int fbase,
                                                      const bf16x8* F, f32x16* d,
                                                      float& lam, float& X2) {
    const float* base = x + row * 32 + h * 8;
    f32x4 va = *(const f32x4*)(base);
    f32x4 vb = *(const f32x4*)(base + 4);
    f32x4 vc = *(const f32x4*)(base + 16);
    f32x4 vd = *(const f32x4*)(base + 20);
    float v[16] = {va[0], va[1], va[2], va[3], vb[0], vb[1], vb[2], vb[3],
                   vc[0], vc[1], vc[2], vc[3], vd[0], vd[1], vd[2], vd[3]};
    float n2 = 0.0f;
#pragma unroll
    for (int i = 0; i < 16; ++i) n2 = fmaf(v[i], v[i], n2);
    n2 = red2h(n2);
    float n = fmaxf(sqrtf(n2), 1e-15f);
    lam = artanh_c(n) / n; // logmap scale, folded past the matvec
    bf16x8 bh[2], bl[2];
#pragma unroll
    for (int kt = 0; kt < 2; ++kt) {
        uint4 hw, lw;
        split_pack2(v[kt * 8 + 0], v[kt * 8 + 1], hw.x, lw.x);
        split_pack2(v[kt * 8 + 2], v[kt * 8 + 3], hw.y, lw.y);
        split_pack2(v[kt * 8 + 4], v[kt * 8 + 5], hw.z, lw.z);
        split_pack2(v[kt * 8 + 6], v[kt * 8 + 7], hw.w, lw.w);
        bh[kt] = __builtin_bit_cast(bf16x8, hw);
        bl[kt] = __builtin_bit_cast(bf16x8, lw);
    }
#pragma unroll
    for (int t = 0; t < 2; ++t) {
        f32x16 c = zero16();
#pragma unroll
        for (int kt = 0; kt < 2; ++kt) {
            int f = fbase + t * 2 + kt;
            bf16x8 wh = F[(2 * f) * 64 + lane];
            bf16x8 wl = F[(2 * f + 1) * 64 + lane];
            c = MFMA32(wh, bh[kt], c);
            c = MFMA32(wl, bh[kt], c);
            c = MFMA32(wh, bl[kt], c);
        }
        d[t] = c;
    }
    expmap_fold32<2>(d, lam, X2);
}

// ---------------------------------------------------------------------------
// Setup: A-operand frags for 32x32x16 (row m = lane&31, k = (lane>>5)*8 + j),
// RNE hi/lo split; W0/W1 K pre-permuted by kperm32. Unchanged from R8.
// ---------------------------------------------------------------------------
__global__ void build_frags(const float* __restrict__ Wc1, const float* __restrict__ Wc2,
                            const float* __restrict__ W0, const float* __restrict__ W1,
                            const float* __restrict__ bc, const float* __restrict__ b0,
                            const float* __restrict__ b1, unsigned short* __restrict__ fout,
                            float* __restrict__ norms) {
    int tid = blockIdx.x * blockDim.x + threadIdx.x;
    const int total = 40 * 512;
    if (tid < total) {
        int p = tid >> 9, within = tid & 511;
        int lane = within >> 3, jj = within & 7;
        int f = p >> 1, isLo = p & 1;
        int m = lane & 31, ha = lane >> 5;
        int kin = ha * 8 + jj; // k within the 16-block
        float w;
        if (f < 4) {
            int t = f >> 1, kt = f & 1;
            w = Wc1[(kt * 16 + kin) * 64 + t * 32 + m];
        } else if (f < 8) {
            int g = f - 4, t = g >> 1, kt = g & 1;
            w = Wc2[(kt * 16 + kin) * 64 + t * 32 + m];
        } else if (f < 16) {
            int g = f - 8, t = g >> 2, kt = g & 3;
            w = W0[kperm32(kt * 16 + kin) * 64 + t * 32 + m];
        } else {
            int kt = f - 16;
            w = W1[kperm32(kt * 16 + kin) * 32 + m];
        }
        unsigned u = __builtin_bit_cast(unsigned, w);
        unsigned r = u + (0x7FFFu + ((u >> 16) & 1u)); // RNE
        unsigned short hi = (unsigned short)(r >> 16);
        float fhi = __builtin_bit_cast(float, (unsigned)hi << 16);
        float res = w - fhi;
        unsigned ul = __builtin_bit_cast(unsigned, res);
        unsigned rl = ul + (0x7FFFu + ((ul >> 16) & 1u));
        fout[tid] = isLo ? (unsigned short)(rl >> 16) : hi;
    } else if (tid < total + 3) {
        int which = tid - total;
        const float* b = which == 0 ? bc : (which == 1 ? b0 : b1);
        int n = which == 2 ? 32 : 64;
        float s = 0.0f;
        for (int i = 0; i < n; ++i) s += b[i] * b[i];
        norms[which] = s;
    }
}

// ---------------------------------------------------------------------------
// Main: 4 waves/block (256 thr), one 32-row tile per wave, frag table in LDS.
// Accumulator arrays explicitly reused (d1 <- layer0, d2 <- layer1) and one
// shared bv[] for all bias vectors, targeting combined regs <=128.
// ---------------------------------------------------------------------------
__global__ void __launch_bounds__(256, 4) poincare_mfma8(
    const float* __restrict__ x1, const float* __restrict__ x2,
    const float* __restrict__ bc, const float* __restrict__ b0,
    const float* __restrict__ b1, const unsigned short* __restrict__ frags,
    const float* __restrict__ norms, float* __restrict__ out, int ntiles) {
    __shared__ __align__(16) unsigned short smem[20480]; // 40 KB frag table

    const int tid = threadIdx.x;
    {
        // stage 40960 B: 256 threads x 10 x 16 B, coalesced, once per block
        const uint4* g = (const uint4*)frags;
        uint4* s = (uint4*)smem;
#pragma unroll
        for (int i = 0; i < 10; ++i) s[tid + i * 256] = g[tid + i * 256];
    }
    __syncthreads();

    const int lane = tid & 63;
    const int wid = tid >> 6;
    const int tile = blockIdx.x * 4 + wid;
    if (tile >= ntiles) return; // after the barrier: safe
    const int r = lane & 31, h = lane >> 5;
    const size_t row = (size_t)tile * 32 + r;

    const bf16x8* F = (const bf16x8*)smem; // F[phys*64 + lane], LDS-resident
    const float bc2 = norms[0], b02 = norms[1], b12 = norms[2];

    // ---- branches
    f32x16 d1[2], d2[2];
    float lam1, X2, lam2, Y2;
    branch_stage32(x1, row, h, lane, 0, F, d1, lam1, X2);
    branch_stage32(x2, row, h, lane, 4, F, d2, lam2, Y2);

    // ---- mobius_add(h1, h2), scales folded
    {
        float C = dotred32<2>(d1, d2);
        float xy = lam1 * lam2 * C;
        float a = 1.0f + 2.0f * xy + Y2;
        float b = 1.0f - X2;
        float den = fmaxf(fmaf(X2, Y2, 1.0f + 2.0f * xy), 1e-15f);
        float inv = 1.0f / den;
        float A = a * lam1, B = b * lam2;
#pragma unroll
        for (int t = 0; t < 2; ++t)
#pragma unroll
            for (int rr = 0; rr < 16; ++rr) d1[t][rr] = fmaf(A, d1[t][rr], B * d2[t][rr]);
        lam1 = inv;
        X2 = (a * a * X2 + 2.0f * a * b * xy + b * b * Y2) * (inv * inv);
    }
    // d2 is dead from here; its registers get reused for layer-1 output.

    // ---- + bc  (bias in D-register order; shared bv[] array)
    f32x16 bv[2];
#pragma unroll
    for (int t = 0; t < 2; ++t) bv[t] = loadb(bc, t * 32, h);
    mobius_bias_fold32<2>(d1, bv, lam1, X2, bc2);
    logmap_fold(lam1, X2);

    // ---- layer 0 (K=64, kperm32'd weights); output overwrites d1
    bf16x8 ah[4], al[4];
    split_d32(d1, ah, al);
#pragma unroll
    for (int t = 0; t < 2; ++t) {
        f32x16 c = zero16();
#pragma unroll
        for (int kt = 0; kt < 4; ++kt) {
            int f = 8 + t * 4 + kt;
            bf16x8 wh = F[(2 * f) * 64 + lane];
            bf16x8 wl = F[(2 * f + 1) * 64 + lane];
            c = MFMA32(wh, ah[kt], c);
            c = MFMA32(wl, ah[kt], c);
            c = MFMA32(wh, al[kt], c);
        }
        d1[t] = c;
    }
    expmap_fold32<2>(d1, lam1, X2);
#pragma unroll
    for (int t = 0; t < 2; ++t) bv[t] = loadb(b0, t * 32, h);
    mobius_bias_fold32<2>(d1, bv, lam1, X2, b02);
    logmap_fold(lam1, X2);

    // ---- layer 1 (N=32); output overwrites d2[0]
    split_d32(d1, ah, al);
    {
        f32x16 c = zero16();
#pragma unroll
        for (int kt = 0; kt < 4; ++kt) {
            int f = 16 + kt;
            bf16x8 wh = F[(2 * f) * 64 + lane];
            bf16x8 wl = F[(2 * f + 1) * 64 + lane];
            c = MFMA32(wh, ah[kt], c);
            c = MFMA32(wl, ah[kt], c);
            c = MFMA32(wh, al[kt], c);
        }
        d2[0] = c;
    }
    expmap_fold32<1>(d2, lam1, X2);

    // ---- final mobius bias, inv folded into the store scale
    bv[0] = loadb(b1, 0, h);
    {
        float C = dotred32<1>(d2, bv);
        float xy = lam1 * C;
        float a = 1.0f + 2.0f * xy + b12;
        float b = 1.0f - X2;
        float den = fmaxf(fmaf(X2, b12, 1.0f + 2.0f * xy), 1e-15f);
        float inv = 1.0f / den;
        float F1 = inv * a * lam1, F2 = inv * b;
#pragma unroll
        for (int g = 0; g < 4; ++g) {
            f32x4 res;
#pragma unroll
            for (int k = 0; k < 4; ++k)
                res[k] = fmaf(F1, d2[0][g * 4 + k], F2 * bv[0][g * 4 + k]);
            *(f32x4*)(out + row * 32 + g * 8 + h * 4) = res;
        }
    }
}

extern "C" void kernel_launch(void* const* d_in, const int* in_sizes, int n_in,
                              void* d_out, int out_size, void* d_ws, size_t ws_size,
                              hipStream_t stream) {
    const float* x1  = (const float*)d_in[0];
    const float* x2  = (const float*)d_in[1];
    const float* Wc1 = (const float*)d_in[2];
    const float* Wc2 = (const float*)d_in[3];
    const float* bc  = (const float*)d_in[4];
    const float* W0  = (const float*)d_in[5];
    const float* b0  = (const float*)d_in[6];
    const float* W1  = (const float*)d_in[7];
    const float* b1  = (const float*)d_in[8];
    float* out = (float*)d_out;

    unsigned short* frags = (unsigned short*)d_ws;            // 40 KB
    float* norms = (float*)((char*)d_ws + 40 * 512 * 2);      // 3 floats

    const int nrows  = in_sizes[0] / 32;
    const int ntiles = nrows / 32;       // 32-row tiles
    const int nblocks = (ntiles + 3) / 4;

    build_frags<<<81, 256, 0, stream>>>(Wc1, Wc2, W0, W1, bc, b0, b1, frags, norms);
    poincare_mfma8<<<nblocks, 256, 0, stream>>>(x1, x2, bc, b0, b1, frags, norms, out, ntiles);
}